// Round 11
// baseline (2271.297 us; speedup 1.0000x reference)
//
#include <hip/hip_runtime.h>
#include <hip/hip_fp16.h>

// ---------------------------------------------------------------------------
// GCN: out = (relu(conv2(relu(conv1(x@We+be)))))@Wo + bo
// GEMMs: fp16 MFMA 16x16x32, fp32 accum.
// Aggregation: NO CSR. Edges bucketed by dst-range (RS=100 nodes/bucket,
// packed u32 = local_dst<<24 | src). agg: one block per bucket, fp32
// accumulator tile in LDS, ds_add_f32 atomics, zero HBM scatter.
// ---------------------------------------------------------------------------

#define WS_ALIGN(x) (((x) + 255) & ~(size_t)255)
#define RS 100   // nodes per bucket; LDS acc = RS*128*4 = 51.2 KB
#define EPT 16   // edges per thread in bucket pass

typedef _Float16 f16x8 __attribute__((ext_vector_type(8)));
typedef float f32x4 __attribute__((ext_vector_type(4)));

// flag=1 => edge_index is int64, flag=0 => int32
__global__ void detect_i64_kernel(const unsigned* __restrict__ p, int* __restrict__ flag) {
    __shared__ int any;
    if (threadIdx.x == 0) any = 0;
    __syncthreads();
    int nz = 0;
    for (int i = threadIdx.x; i < 2048; i += blockDim.x)
        nz |= (p[2 * i + 1] != 0u) ? 1 : 0;
    if (nz) atomicOr(&any, 1);
    __syncthreads();
    if (threadIdx.x == 0) *flag = (any == 0) ? 1 : 0;
}

__global__ void zero_u32_kernel(unsigned* __restrict__ a, int n) {
    int i = blockIdx.x * blockDim.x + threadIdx.x;
    if (i < n) a[i] = 0u;
}

// Bucket edges into nbuck dst-range buckets. LDS ranking + one padded-line
// global atomicAdd per bucket per block (bfill_pad stride = 16 u32 = 64 B).
__global__ __launch_bounds__(256) void bucket_kernel(
    const void* __restrict__ ep, const int* __restrict__ flag,
    unsigned* __restrict__ bkt, unsigned* __restrict__ bfill_pad,
    int E, int nbuck, int capB) {
    __shared__ unsigned lcnt[1024];
    __shared__ unsigned gb[1024];
    const int tid = threadIdx.x;
    for (int i = tid; i < nbuck; i += 256) lcnt[i] = 0;
    __syncthreads();
    const int base = blockIdx.x * (256 * EPT);
    const int i64 = *flag;
    unsigned pk[EPT]; unsigned rk[EPT]; int pr[EPT];
#pragma unroll
    for (int k = 0; k < EPT; ++k) {
        int i = base + k * 256 + tid;
        pr[k] = -1;
        if (i < E) {
            int s, d;
            if (i64) {
                const long long* p = (const long long*)ep;
                s = (int)p[i]; d = (int)p[(size_t)E + i];
            } else {
                const int* p = (const int*)ep;
                s = p[i]; d = p[(size_t)E + i];
            }
            int part = d / RS;
            int ld = d - part * RS;
            pk[k] = ((unsigned)ld << 24) | (unsigned)s;
            pr[k] = part;
            rk[k] = atomicAdd(&lcnt[part], 1u);
        }
    }
    __syncthreads();
    for (int i = tid; i < nbuck; i += 256)
        gb[i] = atomicAdd(&bfill_pad[i << 4], lcnt[i]);
    __syncthreads();
#pragma unroll
    for (int k = 0; k < EPT; ++k) {
        if (pr[k] >= 0) {
            unsigned pos = gb[pr[k]] + rk[k];
            if (pos < (unsigned)capB)
                bkt[(size_t)pr[k] * capB + pos] = pk[k];
        }
    }
}

// deg (hist over bucket) -> dinv, no global atomics (bucket owns its node range)
__global__ __launch_bounds__(256) void dinv_from_bkt_kernel(
    const unsigned* __restrict__ bkt, const unsigned* __restrict__ bfill_pad,
    float* __restrict__ dinv, int capB, int n) {
    __shared__ unsigned hist[RS];
    const int p = blockIdx.x;
    const int tid = threadIdx.x;
    for (int i = tid; i < RS; i += 256) hist[i] = 0;
    __syncthreads();
    unsigned cnt = bfill_pad[p << 4];
    if (cnt > (unsigned)capB) cnt = capB;
    const unsigned* bp = bkt + (size_t)p * capB;
    for (unsigned e = tid; e < cnt; e += 256)
        atomicAdd(&hist[bp[e] >> 24], 1u);
    __syncthreads();
    const int lo = p * RS;
    for (int i = tid; i < RS; i += 256) {
        int node = lo + i;
        if (node < n) dinv[node] = rsqrtf((float)(hist[i] + 1u));
    }
}

// out[i][:] = relu( bias + dinv[i]*( dinv[i]*t[i][:] + sum dinv[s]*t[s][:] ) )
// One block per bucket; fp32 accumulator tile in LDS; ds_add_f32 atomics.
__global__ __launch_bounds__(256) void agg_lds_kernel(
    const unsigned* __restrict__ bkt, const unsigned* __restrict__ bfill_pad, int capB,
    const float* __restrict__ dinv, const __half* __restrict__ t,
    const float* __restrict__ bias, __half* __restrict__ out, int n) {
    __shared__ float acc[RS * 128];
    const int p = blockIdx.x;
    const int lo = p * RS;
    const int tid = threadIdx.x;
    const int l32 = tid & 31;
    const uint2* T = (const uint2*)t;

    // init with self-term dn * t[node]
    for (int r = tid >> 5; r < RS; r += 8) {
        int node = lo + r;
        float4 v = make_float4(0.f, 0.f, 0.f, 0.f);
        if (node < n) {
            float dn = dinv[node];
            uint2 raw = T[(size_t)node * 32 + l32];
            float2 f01 = __half22float2(*(const __half2*)&raw.x);
            float2 f23 = __half22float2(*(const __half2*)&raw.y);
            v = make_float4(f01.x * dn, f01.y * dn, f23.x * dn, f23.y * dn);
        }
        *(float4*)&acc[r * 128 + l32 * 4] = v;
    }
    __syncthreads();

    unsigned cnt = bfill_pad[p << 4];
    if (cnt > (unsigned)capB) cnt = capB;
    const unsigned* bp = bkt + (size_t)p * capB;
    // 2 edges per wave per iteration (32 lanes each), 8 per block-iteration
    for (unsigned e = (unsigned)(tid >> 5); e < cnt; e += 8) {
        unsigned u = bp[e];
        int s = (int)(u & 0xFFFFFFu);
        int ld = (int)(u >> 24);
        float w = dinv[s];
        uint2 raw = T[(size_t)s * 32 + l32];
        float2 f01 = __half22float2(*(const __half2*)&raw.x);
        float2 f23 = __half22float2(*(const __half2*)&raw.y);
        float* ap = &acc[ld * 128 + l32 * 4];
        atomicAdd(ap + 0, f01.x * w);
        atomicAdd(ap + 1, f01.y * w);
        atomicAdd(ap + 2, f23.x * w);
        atomicAdd(ap + 3, f23.y * w);
    }
    __syncthreads();

    // epilogue: relu(bias + dn*acc) -> fp16
    for (int r = tid >> 5; r < RS; r += 8) {
        int node = lo + r;
        if (node >= n) continue;
        float dn = dinv[node];
        float4 a = *(float4*)&acc[r * 128 + l32 * 4];
        float4 b4 = ((const float4*)bias)[l32];
        float ox = fmaxf(fmaf(a.x, dn, b4.x), 0.f);
        float oy = fmaxf(fmaf(a.y, dn, b4.y), 0.f);
        float oz = fmaxf(fmaf(a.z, dn, b4.z), 0.f);
        float ow = fmaxf(fmaf(a.w, dn, b4.w), 0.f);
        __half2 h01 = __floats2half2_rn(ox, oy);
        __half2 h23 = __floats2half2_rn(oz, ow);
        uint2 packed;
        packed.x = *(unsigned*)&h01;
        packed.y = *(unsigned*)&h23;
        ((uint2*)(out + (size_t)node * 128))[l32] = packed;
    }
}

// fp32 -> fp16, 8 elems/thread
__global__ void f32_to_f16_kernel(const float* __restrict__ in, __half* __restrict__ out, int n8) {
    int i = blockIdx.x * blockDim.x + threadIdx.x;
    if (i >= n8) return;
    const float4* in4 = (const float4*)in;
    float4 v0 = in4[2 * i], v1 = in4[2 * i + 1];
    __half2 h0 = __floats2half2_rn(v0.x, v0.y);
    __half2 h1 = __floats2half2_rn(v0.z, v0.w);
    __half2 h2 = __floats2half2_rn(v1.x, v1.y);
    __half2 h3 = __floats2half2_rn(v1.z, v1.w);
    uint4 p;
    p.x = *(unsigned*)&h0; p.y = *(unsigned*)&h1;
    p.z = *(unsigned*)&h2; p.w = *(unsigned*)&h3;
    *(uint4*)(out + (size_t)i * 8) = p;
}

// Build fragment-ready W: Wf[((c0*4+ks)*64+lane)*8+j] = f16(W[ks*32+(lane>>4)*8+j][c0*16+(lane&15)])
__global__ void wfrag_kernel(const float* __restrict__ W, __half* __restrict__ Wf, int ncol) {
    int t = blockIdx.x * blockDim.x + threadIdx.x;
    int total = (ncol >> 4) * 4 * 64;
    if (t >= total) return;
    int lane = t & 63;
    int ks = (t >> 6) & 3;
    int c0 = t >> 8;
    int colw = c0 * 16 + (lane & 15);
    int k0 = ks * 32 + ((lane >> 4) << 3);
    __half vals[8];
#pragma unroll
    for (int j = 0; j < 8; ++j) vals[j] = __float2half(W[(size_t)(k0 + j) * ncol + colw]);
    *(uint4*)(Wf + (size_t)t * 8) = *(uint4*)vals;
}

// C[n,ncol] = A[n,128](f16) @ W[128,ncol] (+bias). MFMA f16, fp32 accum.
__global__ __launch_bounds__(256) void gemm_mfma_kernel(
    const __half* __restrict__ A, const __half* __restrict__ Wf,
    const float* __restrict__ bias, void* __restrict__ C,
    int n, int ncol, int c_fp32) {
    const int wave = threadIdx.x >> 6;
    const int lane = threadIdx.x & 63;
    const int row0 = blockIdx.x * 64 + wave * 16;
    int ar = row0 + (lane & 15);
    if (ar >= n) ar = n - 1;
    const __half* abase = A + (size_t)ar * 128 + ((lane >> 4) << 3);
    f16x8 a0 = *(const f16x8*)(abase);
    f16x8 a1 = *(const f16x8*)(abase + 32);
    f16x8 a2 = *(const f16x8*)(abase + 64);
    f16x8 a3 = *(const f16x8*)(abase + 96);
    const int ncc = ncol >> 4;
    const int cic = lane & 15;
    const int rbase = (lane >> 4) << 2;
    for (int c0 = 0; c0 < ncc; ++c0) {
        const f16x8* wf = (const f16x8*)Wf + (size_t)c0 * 256 + lane;
        f32x4 acc = {0.f, 0.f, 0.f, 0.f};
        acc = __builtin_amdgcn_mfma_f32_16x16x32_f16(a0, wf[0],   acc, 0, 0, 0);
        acc = __builtin_amdgcn_mfma_f32_16x16x32_f16(a1, wf[64],  acc, 0, 0, 0);
        acc = __builtin_amdgcn_mfma_f32_16x16x32_f16(a2, wf[128], acc, 0, 0, 0);
        acc = __builtin_amdgcn_mfma_f32_16x16x32_f16(a3, wf[192], acc, 0, 0, 0);
        int colc = (c0 << 4) + cic;
        float bv = bias ? bias[colc] : 0.f;
#pragma unroll
        for (int r = 0; r < 4; ++r) {
            int row = row0 + rbase + r;
            if (row < n) {
                float v = acc[r] + bv;
                if (c_fp32) ((float*)C)[(size_t)row * ncol + colc] = v;
                else        ((__half*)C)[(size_t)row * ncol + colc] = __float2half(v);
            }
        }
    }
}

extern "C" void kernel_launch(void* const* d_in, const int* in_sizes, int n_in,
                              void* d_out, int out_size, void* d_ws, size_t ws_size,
                              hipStream_t stream) {
    const float* x  = (const float*)d_in[0];
    const void*  ei = d_in[1];
    const float* We = (const float*)d_in[2];
    const float* be = (const float*)d_in[3];
    const float* W1 = (const float*)d_in[4];
    const float* b1 = (const float*)d_in[5];
    const float* W2 = (const float*)d_in[6];
    const float* b2 = (const float*)d_in[7];
    const float* Wo = (const float*)d_in[8];
    const float* bo = (const float*)d_in[9];
    const int N = in_sizes[0] / 128;
    const int E = in_sizes[1] / 2;
    const int NC = in_sizes[9];                 // NUM_CLASS = 64
    const int nbuck = (N + RS - 1) / RS;        // 500 for N=50000 (<=1024)
    const int capB = (E + nbuck - 1) / nbuck + 512;

    char* ws = (char*)d_ws;
    size_t off = 0;
    int*      flag = (int*)(ws + off);      off += 256;
    unsigned* bfil = (unsigned*)(ws + off); off += WS_ALIGN((size_t)nbuck * 64);
    unsigned* bkt  = (unsigned*)(ws + off); off += WS_ALIGN((size_t)nbuck * capB * 4);
    float*    dinv = (float*)(ws + off);    off += WS_ALIGN((size_t)N * 4);
    __half*   WeF  = (__half*)(ws + off);   off += WS_ALIGN((size_t)128 * 128 * 2);
    __half*   W1F  = (__half*)(ws + off);   off += WS_ALIGN((size_t)128 * 128 * 2);
    __half*   W2F  = (__half*)(ws + off);   off += WS_ALIGN((size_t)128 * 128 * 2);
    __half*   WoF  = (__half*)(ws + off);   off += WS_ALIGN((size_t)128 * 64 * 2);
    __half*   xH   = (__half*)(ws + off);   off += WS_ALIGN((size_t)N * 128 * 2);
    __half*   hA   = (__half*)(ws + off);   off += WS_ALIGN((size_t)N * 128 * 2);
    __half*   tH   = (__half*)(ws + off);   off += WS_ALIGN((size_t)N * 128 * 2);

    const int nb_bucket = (E + 256 * EPT - 1) / (256 * EPT);
    const int nb_zero = (nbuck * 16 + 255) / 256;
    dim3 blk(256);

    // bucket build + dinv
    detect_i64_kernel<<<1, 256, 0, stream>>>((const unsigned*)ei, flag);
    zero_u32_kernel<<<nb_zero, blk, 0, stream>>>(bfil, nbuck * 16);
    bucket_kernel<<<nb_bucket, blk, 0, stream>>>(ei, flag, bkt, bfil, E, nbuck, capB);
    dinv_from_bkt_kernel<<<nbuck, blk, 0, stream>>>(bkt, bfil, dinv, capB, N);

    // weight fragments + x fp16
    wfrag_kernel<<<8, 256, 0, stream>>>(We, WeF, 128);
    wfrag_kernel<<<8, 256, 0, stream>>>(W1, W1F, 128);
    wfrag_kernel<<<8, 256, 0, stream>>>(W2, W2F, 128);
    wfrag_kernel<<<4, 256, 0, stream>>>(Wo, WoF, NC);
    f32_to_f16_kernel<<<(N * 16 + 255) / 256, 256, 0, stream>>>(x, xH, N * 16);

    const int gemm_blocks = (N + 63) / 64;

    // encoder: h0 = x@We + be -> hA (fp16)
    gemm_mfma_kernel<<<gemm_blocks, blk, 0, stream>>>(xH, WeF, be, hA, N, 128, 0);
    // conv1: t1 = h0@W1 -> tH ; a1 = relu(Agg(t1)+b1) -> hA
    gemm_mfma_kernel<<<gemm_blocks, blk, 0, stream>>>(hA, W1F, nullptr, tH, N, 128, 0);
    agg_lds_kernel<<<nbuck, blk, 0, stream>>>(bkt, bfil, capB, dinv, tH, b1, hA, N);
    // conv2: t2 = a1@W2 -> tH ; a2 = relu(Agg(t2)+b2) -> hA
    gemm_mfma_kernel<<<gemm_blocks, blk, 0, stream>>>(hA, W2F, nullptr, tH, N, 128, 0);
    agg_lds_kernel<<<nbuck, blk, 0, stream>>>(bkt, bfil, capB, dinv, tH, b2, hA, N);
    // decoder: out = a2@Wo + bo -> d_out (fp32)
    gemm_mfma_kernel<<<gemm_blocks, blk, 0, stream>>>(hA, WoF, bo, d_out, N, NC, 1);
}

// Round 12
// 227.165 us; speedup vs baseline: 9.9985x; 9.9985x over previous
//
#include <hip/hip_runtime.h>
#include <hip/hip_fp16.h>

// ---------------------------------------------------------------------------
// GCN: out = (relu(conv2(relu(conv1(x@We+be)))))@Wo + bo
// GEMMs: fp16 MFMA 16x16x32, fp32 accum. Aggregation: CSR pull (per-node wave).
// CSR build: bucket edges by dst-range (RS=100) -> scan bucket counts ->
// per-bucket LDS histogram + contiguous-window scatter (no global-atomic count,
// no cross-XCD scattered fill).
// ---------------------------------------------------------------------------

#define WS_ALIGN(x) (((x) + 255) & ~(size_t)255)
#define RS 100   // nodes per bucket
#define EPT 16   // edges per thread in bucket pass

typedef _Float16 f16x8 __attribute__((ext_vector_type(8)));
typedef float f32x4 __attribute__((ext_vector_type(4)));

// flag=1 => edge_index is int64, flag=0 => int32
__global__ void detect_i64_kernel(const unsigned* __restrict__ p, int* __restrict__ flag) {
    __shared__ int any;
    if (threadIdx.x == 0) any = 0;
    __syncthreads();
    int nz = 0;
    for (int i = threadIdx.x; i < 2048; i += blockDim.x)
        nz |= (p[2 * i + 1] != 0u) ? 1 : 0;
    if (nz) atomicOr(&any, 1);
    __syncthreads();
    if (threadIdx.x == 0) *flag = (any == 0) ? 1 : 0;
}

__global__ void zero_u32_kernel(unsigned* __restrict__ a, int n) {
    int i = blockIdx.x * blockDim.x + threadIdx.x;
    if (i < n) a[i] = 0u;
}

// Bucket edges into nbuck dst-range buckets. LDS ranking + one padded-line
// global atomicAdd per bucket per block (bfill_pad stride = 16 u32 = 64 B).
__global__ __launch_bounds__(256) void bucket_kernel(
    const void* __restrict__ ep, const int* __restrict__ flag,
    unsigned* __restrict__ bkt, unsigned* __restrict__ bfill_pad,
    int E, int nbuck, int capB) {
    __shared__ unsigned lcnt[1024];
    __shared__ unsigned gb[1024];
    const int tid = threadIdx.x;
    for (int i = tid; i < nbuck; i += 256) lcnt[i] = 0;
    __syncthreads();
    const int base = blockIdx.x * (256 * EPT);
    const int i64 = *flag;
    unsigned pk[EPT]; unsigned rk[EPT]; int pr[EPT];
#pragma unroll
    for (int k = 0; k < EPT; ++k) {
        int i = base + k * 256 + tid;
        pr[k] = -1;
        if (i < E) {
            int s, d;
            if (i64) {
                const long long* p = (const long long*)ep;
                s = (int)p[i]; d = (int)p[(size_t)E + i];
            } else {
                const int* p = (const int*)ep;
                s = p[i]; d = p[(size_t)E + i];
            }
            int part = d / RS;
            int ld = d - part * RS;
            pk[k] = ((unsigned)ld << 24) | (unsigned)s;
            pr[k] = part;
            rk[k] = atomicAdd(&lcnt[part], 1u);
        }
    }
    __syncthreads();
    for (int i = tid; i < nbuck; i += 256)
        gb[i] = atomicAdd(&bfill_pad[i << 4], lcnt[i]);
    __syncthreads();
#pragma unroll
    for (int k = 0; k < EPT; ++k) {
        if (pr[k] >= 0) {
            unsigned pos = gb[pr[k]] + rk[k];
            if (pos < (unsigned)capB)
                bkt[(size_t)pr[k] * capB + pos] = pk[k];
        }
    }
}

// Exclusive scan of bucket counts -> ebase; rowp[n] = total.
__global__ __launch_bounds__(512) void bucket_scan_kernel(
    const unsigned* __restrict__ bfill_pad, unsigned* __restrict__ ebase,
    int* __restrict__ rowp, int nbuck, int capB, int n) {
    __shared__ unsigned lds[512];
    const int tid = threadIdx.x;
    unsigned v = 0;
    if (tid < nbuck) {
        v = bfill_pad[tid << 4];
        if (v > (unsigned)capB) v = capB;
    }
    lds[tid] = v;
    __syncthreads();
    for (int off = 1; off < 512; off <<= 1) {
        unsigned add = (tid >= off) ? lds[tid - off] : 0;
        __syncthreads();
        lds[tid] += add;
        __syncthreads();
    }
    if (tid < nbuck) ebase[tid] = lds[tid] - v;  // exclusive
    if (tid == 511) rowp[n] = (int)lds[511];
}

// One block per bucket: LDS hist -> rowp/dinv; scatter col into the bucket's
// contiguous CSR window.
__global__ __launch_bounds__(256) void csr_from_bucket_kernel(
    const unsigned* __restrict__ bkt, const unsigned* __restrict__ bfill_pad,
    const unsigned* __restrict__ ebase,
    int* __restrict__ rowp, float* __restrict__ dinv, int* __restrict__ col,
    int capB, int n) {
    __shared__ unsigned hist[RS];
    __shared__ int fillo[RS];
    const int p = blockIdx.x;
    const int tid = threadIdx.x;
    for (int i = tid; i < RS; i += 256) hist[i] = 0;
    __syncthreads();
    unsigned cnt = bfill_pad[p << 4];
    if (cnt > (unsigned)capB) cnt = capB;
    const unsigned* bp = bkt + (size_t)p * capB;
    for (unsigned e = tid; e < cnt; e += 256)
        atomicAdd(&hist[bp[e] >> 24], 1u);
    __syncthreads();
    if (tid == 0) {
        int run = (int)ebase[p];
        for (int i = 0; i < RS; ++i) { fillo[i] = run; run += (int)hist[i]; }
    }
    __syncthreads();
    const int lo = p * RS;
    for (int i = tid; i < RS; i += 256) {
        int node = lo + i;
        if (node < n) {
            rowp[node] = fillo[i];
            dinv[node] = rsqrtf((float)(hist[i] + 1u));
        }
    }
    for (unsigned e = tid; e < cnt; e += 256) {
        unsigned u = bp[e];
        int ld = (int)(u >> 24);
        int pos = atomicAdd(&fillo[ld], 1);
        col[pos] = (int)(u & 0xFFFFFFu);
    }
}

// out[i][:] = relu( bias + dinv[i]*( dinv[i]*t[i][:] + sum_j dinv[col[j]]*t[col[j]][:] ) )
// t fp16 (N x 128); out fp16. 32 lanes/node, 4 halves per lane; fp32 accum.
__global__ __launch_bounds__(256) void agg_pull_kernel(
    const int* __restrict__ rowp, const int* __restrict__ col,
    const float* __restrict__ dinv, const __half* __restrict__ t,
    const float* __restrict__ bias, __half* __restrict__ out, int n) {
    int node = blockIdx.x * 8 + (threadIdx.x >> 5);
    int lane = threadIdx.x & 31;
    if (node >= n) return;
    const uint2* T = (const uint2*)t;
    int j0 = rowp[node], j1 = rowp[node + 1];
    float dn = dinv[node];

#define H4_TO_F(raw, fa, fb)                                   \
    float2 fa = __half22float2(*(const __half2*)&raw.x);       \
    float2 fb = __half22float2(*(const __half2*)&raw.y);

    uint2 sraw = T[(size_t)node * 32 + lane];
    H4_TO_F(sraw, s01, s23)
    float4 acc;
    acc.x = s01.x * dn; acc.y = s01.y * dn; acc.z = s23.x * dn; acc.w = s23.y * dn;

    int j = j0;
    for (; j + 3 < j1; j += 4) {
        int c0 = col[j], c1 = col[j + 1], c2 = col[j + 2], c3 = col[j + 3];
        float w0 = dinv[c0], w1 = dinv[c1], w2 = dinv[c2], w3 = dinv[c3];
        uint2 r0 = T[(size_t)c0 * 32 + lane];
        uint2 r1 = T[(size_t)c1 * 32 + lane];
        uint2 r2 = T[(size_t)c2 * 32 + lane];
        uint2 r3 = T[(size_t)c3 * 32 + lane];
        H4_TO_F(r0, a01, a23)
        H4_TO_F(r1, b01, b23)
        H4_TO_F(r2, c01, c23)
        H4_TO_F(r3, d01, d23)
        acc.x = fmaf(a01.x, w0, acc.x); acc.y = fmaf(a01.y, w0, acc.y);
        acc.z = fmaf(a23.x, w0, acc.z); acc.w = fmaf(a23.y, w0, acc.w);
        acc.x = fmaf(b01.x, w1, acc.x); acc.y = fmaf(b01.y, w1, acc.y);
        acc.z = fmaf(b23.x, w1, acc.z); acc.w = fmaf(b23.y, w1, acc.w);
        acc.x = fmaf(c01.x, w2, acc.x); acc.y = fmaf(c01.y, w2, acc.y);
        acc.z = fmaf(c23.x, w2, acc.z); acc.w = fmaf(c23.y, w2, acc.w);
        acc.x = fmaf(d01.x, w3, acc.x); acc.y = fmaf(d01.y, w3, acc.y);
        acc.z = fmaf(d23.x, w3, acc.z); acc.w = fmaf(d23.y, w3, acc.w);
    }
    for (; j < j1; ++j) {
        int c = col[j];
        float w = dinv[c];
        uint2 raw = T[(size_t)c * 32 + lane];
        H4_TO_F(raw, f01, f23)
        acc.x = fmaf(f01.x, w, acc.x); acc.y = fmaf(f01.y, w, acc.y);
        acc.z = fmaf(f23.x, w, acc.z); acc.w = fmaf(f23.y, w, acc.w);
    }
#undef H4_TO_F
    float4 b = ((const float4*)bias)[lane];
    float ox = fmaxf(fmaf(acc.x, dn, b.x), 0.f);
    float oy = fmaxf(fmaf(acc.y, dn, b.y), 0.f);
    float oz = fmaxf(fmaf(acc.z, dn, b.z), 0.f);
    float ow = fmaxf(fmaf(acc.w, dn, b.w), 0.f);
    __half2 h01 = __floats2half2_rn(ox, oy);
    __half2 h23 = __floats2half2_rn(oz, ow);
    uint2 packed;
    packed.x = *(unsigned*)&h01;
    packed.y = *(unsigned*)&h23;
    ((uint2*)(out + (size_t)node * 128))[lane] = packed;
}

// fp32 -> fp16, 8 elems/thread
__global__ void f32_to_f16_kernel(const float* __restrict__ in, __half* __restrict__ out, int n8) {
    int i = blockIdx.x * blockDim.x + threadIdx.x;
    if (i >= n8) return;
    const float4* in4 = (const float4*)in;
    float4 v0 = in4[2 * i], v1 = in4[2 * i + 1];
    __half2 h0 = __floats2half2_rn(v0.x, v0.y);
    __half2 h1 = __floats2half2_rn(v0.z, v0.w);
    __half2 h2 = __floats2half2_rn(v1.x, v1.y);
    __half2 h3 = __floats2half2_rn(v1.z, v1.w);
    uint4 p;
    p.x = *(unsigned*)&h0; p.y = *(unsigned*)&h1;
    p.z = *(unsigned*)&h2; p.w = *(unsigned*)&h3;
    *(uint4*)(out + (size_t)i * 8) = p;
}

// Build fragment-ready W: Wf[((c0*4+ks)*64+lane)*8+j] = f16(W[ks*32+(lane>>4)*8+j][c0*16+(lane&15)])
__global__ void wfrag_kernel(const float* __restrict__ W, __half* __restrict__ Wf, int ncol) {
    int t = blockIdx.x * blockDim.x + threadIdx.x;
    int total = (ncol >> 4) * 4 * 64;
    if (t >= total) return;
    int lane = t & 63;
    int ks = (t >> 6) & 3;
    int c0 = t >> 8;
    int colw = c0 * 16 + (lane & 15);
    int k0 = ks * 32 + ((lane >> 4) << 3);
    __half vals[8];
#pragma unroll
    for (int j = 0; j < 8; ++j) vals[j] = __float2half(W[(size_t)(k0 + j) * ncol + colw]);
    *(uint4*)(Wf + (size_t)t * 8) = *(uint4*)vals;
}

// C[n,ncol] = A[n,128](f16) @ W[128,ncol] (+bias). MFMA f16, fp32 accum.
__global__ __launch_bounds__(256) void gemm_mfma_kernel(
    const __half* __restrict__ A, const __half* __restrict__ Wf,
    const float* __restrict__ bias, void* __restrict__ C,
    int n, int ncol, int c_fp32) {
    const int wave = threadIdx.x >> 6;
    const int lane = threadIdx.x & 63;
    const int row0 = blockIdx.x * 64 + wave * 16;
    int ar = row0 + (lane & 15);
    if (ar >= n) ar = n - 1;
    const __half* abase = A + (size_t)ar * 128 + ((lane >> 4) << 3);
    f16x8 a0 = *(const f16x8*)(abase);
    f16x8 a1 = *(const f16x8*)(abase + 32);
    f16x8 a2 = *(const f16x8*)(abase + 64);
    f16x8 a3 = *(const f16x8*)(abase + 96);
    const int ncc = ncol >> 4;
    const int cic = lane & 15;
    const int rbase = (lane >> 4) << 2;
    for (int c0 = 0; c0 < ncc; ++c0) {
        const f16x8* wf = (const f16x8*)Wf + (size_t)c0 * 256 + lane;
        f32x4 acc = {0.f, 0.f, 0.f, 0.f};
        acc = __builtin_amdgcn_mfma_f32_16x16x32_f16(a0, wf[0],   acc, 0, 0, 0);
        acc = __builtin_amdgcn_mfma_f32_16x16x32_f16(a1, wf[64],  acc, 0, 0, 0);
        acc = __builtin_amdgcn_mfma_f32_16x16x32_f16(a2, wf[128], acc, 0, 0, 0);
        acc = __builtin_amdgcn_mfma_f32_16x16x32_f16(a3, wf[192], acc, 0, 0, 0);
        int colc = (c0 << 4) + cic;
        float bv = bias ? bias[colc] : 0.f;
#pragma unroll
        for (int r = 0; r < 4; ++r) {
            int row = row0 + rbase + r;
            if (row < n) {
                float v = acc[r] + bv;
                if (c_fp32) ((float*)C)[(size_t)row * ncol + colc] = v;
                else        ((__half*)C)[(size_t)row * ncol + colc] = __float2half(v);
            }
        }
    }
}

extern "C" void kernel_launch(void* const* d_in, const int* in_sizes, int n_in,
                              void* d_out, int out_size, void* d_ws, size_t ws_size,
                              hipStream_t stream) {
    const float* x  = (const float*)d_in[0];
    const void*  ei = d_in[1];
    const float* We = (const float*)d_in[2];
    const float* be = (const float*)d_in[3];
    const float* W1 = (const float*)d_in[4];
    const float* b1 = (const float*)d_in[5];
    const float* W2 = (const float*)d_in[6];
    const float* b2 = (const float*)d_in[7];
    const float* Wo = (const float*)d_in[8];
    const float* bo = (const float*)d_in[9];
    const int N = in_sizes[0] / 128;
    const int E = in_sizes[1] / 2;
    const int NC = in_sizes[9];                 // NUM_CLASS = 64
    const int nbuck = (N + RS - 1) / RS;        // 500 for N=50000 (<=512)
    const int capB = (E + nbuck - 1) / nbuck + 512;

    char* ws = (char*)d_ws;
    size_t off = 0;
    int*      flag = (int*)(ws + off);      off += 256;
    unsigned* bfil = (unsigned*)(ws + off); off += WS_ALIGN((size_t)nbuck * 64);
    unsigned* ebas = (unsigned*)(ws + off); off += WS_ALIGN((size_t)nbuck * 4);
    unsigned* bkt  = (unsigned*)(ws + off); off += WS_ALIGN((size_t)nbuck * capB * 4);
    float*    dinv = (float*)(ws + off);    off += WS_ALIGN((size_t)N * 4);
    int*      rowp = (int*)(ws + off);      off += WS_ALIGN((size_t)(N + 1) * 4);
    int*      colw = (int*)(ws + off);      off += WS_ALIGN((size_t)E * 4);
    __half*   WeF  = (__half*)(ws + off);   off += WS_ALIGN((size_t)128 * 128 * 2);
    __half*   W1F  = (__half*)(ws + off);   off += WS_ALIGN((size_t)128 * 128 * 2);
    __half*   W2F  = (__half*)(ws + off);   off += WS_ALIGN((size_t)128 * 128 * 2);
    __half*   WoF  = (__half*)(ws + off);   off += WS_ALIGN((size_t)128 * 64 * 2);
    __half*   xH   = (__half*)(ws + off);   off += WS_ALIGN((size_t)N * 128 * 2);
    __half*   hA   = (__half*)(ws + off);   off += WS_ALIGN((size_t)N * 128 * 2);
    __half*   tH   = (__half*)(ws + off);   off += WS_ALIGN((size_t)N * 128 * 2);

    const int nb_bucket = (E + 256 * EPT - 1) / (256 * EPT);
    const int nb_zero = (nbuck * 16 + 255) / 256;
    dim3 blk(256);

    // CSR build via buckets
    detect_i64_kernel<<<1, 256, 0, stream>>>((const unsigned*)ei, flag);
    zero_u32_kernel<<<nb_zero, blk, 0, stream>>>(bfil, nbuck * 16);
    bucket_kernel<<<nb_bucket, blk, 0, stream>>>(ei, flag, bkt, bfil, E, nbuck, capB);
    bucket_scan_kernel<<<1, 512, 0, stream>>>(bfil, ebas, rowp, nbuck, capB, N);
    csr_from_bucket_kernel<<<nbuck, blk, 0, stream>>>(bkt, bfil, ebas, rowp, dinv, colw, capB, N);

    // weight fragments + x fp16
    wfrag_kernel<<<8, 256, 0, stream>>>(We, WeF, 128);
    wfrag_kernel<<<8, 256, 0, stream>>>(W1, W1F, 128);
    wfrag_kernel<<<8, 256, 0, stream>>>(W2, W2F, 128);
    wfrag_kernel<<<4, 256, 0, stream>>>(Wo, WoF, NC);
    f32_to_f16_kernel<<<(N * 16 + 255) / 256, 256, 0, stream>>>(x, xH, N * 16);

    const int gemm_blocks = (N + 63) / 64;
    const int agg_blocks = (N + 7) / 8;

    // encoder: h0 = x@We + be -> hA (fp16)
    gemm_mfma_kernel<<<gemm_blocks, blk, 0, stream>>>(xH, WeF, be, hA, N, 128, 0);
    // conv1: t1 = h0@W1 -> tH ; a1 = relu(Agg(t1)+b1) -> hA
    gemm_mfma_kernel<<<gemm_blocks, blk, 0, stream>>>(hA, W1F, nullptr, tH, N, 128, 0);
    agg_pull_kernel<<<agg_blocks, blk, 0, stream>>>(rowp, colw, dinv, tH, b1, hA, N);
    // conv2: t2 = a1@W2 -> tH ; a2 = relu(Agg(t2)+b2) -> hA
    gemm_mfma_kernel<<<gemm_blocks, blk, 0, stream>>>(hA, W2F, nullptr, tH, N, 128, 0);
    agg_pull_kernel<<<agg_blocks, blk, 0, stream>>>(rowp, colw, dinv, tH, b2, hA, N);
    // decoder: out = a2@Wo + bo -> d_out (fp32)
    gemm_mfma_kernel<<<gemm_blocks, blk, 0, stream>>>(hA, WoF, bo, d_out, N, NC, 1);
}